// Round 4
// baseline (377.232 us; speedup 1.0000x reference)
//
#include <hip/hip_runtime.h>
#include <hip/hip_bf16.h>

// SelfAttention B=4 H=16 L=2048 D=64 fp32 in/out.
// Round 4 = round 3 with the compile fix (manual RNE bf16 pack instead of
// __builtin_bit_cast of __hip_bfloat162, which is not trivially copyable).
//   QT=128 q/block (32/wave), 1024 blocks = 4 blocks/CU (was 2 -> Occ 22%).
//   Even/odd key permutation in Ks: lane's two scores are adjacent keys ->
//   packed b32 P-writes, float2 bias loads, int2 mask load.
//   p = exp2(fma(s, 0.125*log2e, fma(bias, log2e, -12*log2e))), 1 v_exp_f32.
//   Row-sum l via ones-column MFMA -> no epilogue shuffles.
//   LDS 29.7 KB; __launch_bounds__(256,4) caps VGPR at 128.

constexpr int kH = 16;
constexpr int kL = 2048;
constexpr int kD = 64;

typedef __attribute__((ext_vector_type(8))) short bf16x8;
typedef __attribute__((ext_vector_type(4))) float f32x4;

__device__ __forceinline__ unsigned short f2bf(float f) {
  unsigned u = __float_as_uint(f);
  u += 0x7FFF + ((u >> 16) & 1);          // round-to-nearest-even
  return (unsigned short)(u >> 16);
}
__device__ __forceinline__ unsigned packbf2(float a, float b) {
  return (unsigned)f2bf(a) | ((unsigned)f2bf(b) << 16);
}

__global__ __launch_bounds__(256, 4)
void attn_fwd(const float* __restrict__ Qg, const float* __restrict__ Kg,
              const float* __restrict__ Vg, const int* __restrict__ maskg,
              const float* __restrict__ biasg, float* __restrict__ outg) {
  // LDS: Ks 2 bufs x 32 keys x 72 halves = 9216 B   [0, 9216)
  //      Vt 2 bufs x 64 d   x 40 halves = 10240 B   [9216, 19456)
  //      Ps 4 waves x 32 q  x 40 halves = 10240 B   [19456, 29696)
  // prologue aliases [0, 18432) as Qs 128 x 72 halves
  __shared__ __align__(16) char smem[29696];
  unsigned short* const KsBase = (unsigned short*)smem;
  unsigned short* const VtBase = (unsigned short*)(smem + 9216);
  unsigned short* const QsAll  = (unsigned short*)smem;

  const int tid  = threadIdx.x;
  const int lane = tid & 63;
  const int w    = tid >> 6;        // wave 0..3, owns q-rows w*32 .. w*32+31
  const int col  = lane & 15;
  const int quad = lane >> 4;
  const int h  = blockIdx.x;
  const int qb = blockIdx.y;
  const int b  = blockIdx.z;
  const int q0 = qb * 128;

  unsigned short* const Ps = (unsigned short*)(smem + 19456) + w * 1280;

  const size_t bh = (size_t)b * kH + h;
  const float4* const Q4 = (const float4*)(Qg + (bh * kL + q0) * kD);
  const float4* const K4 = (const float4*)(Kg + bh * kL * kD);
  const float4* const V4 = (const float4*)(Vg + bh * kL * kD);
  const float*  const brow = biasg + (size_t)b * kL * kL;
  const int*    const mrow = maskg + b * kL;

  // ---- prologue: Q fp32->bf16 into Qs (128 rows x 16 float4), load frags ----
#pragma unroll
  for (int i = 0; i < 8; ++i) {
    const int slot = tid + i * 256;
    const int row = slot >> 4, dc = slot & 15;
    const float4 v = Q4[slot];
    *(uint2*)&QsAll[row * 72 + dc * 4] =
        make_uint2(packbf2(v.x, v.y), packbf2(v.z, v.w));
  }
  __syncthreads();
  bf16x8 qf[2][2];
#pragma unroll
  for (int qt = 0; qt < 2; ++qt)
#pragma unroll
    for (int kc = 0; kc < 2; ++kc)
      qf[qt][kc] = *(const bf16x8*)
          &QsAll[(w * 32 + qt * 16 + col) * 72 + kc * 32 + quad * 8];
  __syncthreads();                          // Qs dead; smem now Ks/Vt/Ps

  // staging index split (coalesced 256B row reads)
  const int keyA = tid >> 4, dcA = tid & 15;   // K: global keys keyA, keyA+16
  // even/odd permuted Ks row: key j -> row (j&1)*16 + j/2  (keyA+16 -> rA+8)
  const int rA   = ((keyA & 1) << 4) + (keyA >> 1);
  const int jp   = tid >> 4, dcv = tid & 15;   // V: key pair (2jp, 2jp+1)

  // ---- stage tile 0 into buf 0 ----
  {
    const float4 a  = K4[keyA * 16 + dcA];
    const float4 c  = K4[(16 + keyA) * 16 + dcA];
    const float4 v0 = V4[(2 * jp) * 16 + dcv];
    const float4 v1 = V4[(2 * jp + 1) * 16 + dcv];
    *(uint2*)&KsBase[rA * 72 + dcA * 4] =
        make_uint2(packbf2(a.x, a.y), packbf2(a.z, a.w));
    *(uint2*)&KsBase[(rA + 8) * 72 + dcA * 4] =
        make_uint2(packbf2(c.x, c.y), packbf2(c.z, c.w));
    *(unsigned*)&VtBase[(dcv * 4 + 0) * 40 + 2 * jp] = packbf2(v0.x, v1.x);
    *(unsigned*)&VtBase[(dcv * 4 + 1) * 40 + 2 * jp] = packbf2(v0.y, v1.y);
    *(unsigned*)&VtBase[(dcv * 4 + 2) * 40 + 2 * jp] = packbf2(v0.z, v1.z);
    *(unsigned*)&VtBase[(dcv * 4 + 3) * 40 + 2 * jp] = packbf2(v0.w, v1.w);
  }

  f32x4 oacc[2][4];                         // [qtile][dtile]
  f32x4 lacc[2];                            // row sums via ones-MFMA
  const f32x4 z4 = {0.f, 0.f, 0.f, 0.f};
#pragma unroll
  for (int qt = 0; qt < 2; ++qt) {
    lacc[qt] = z4;
#pragma unroll
    for (int dt = 0; dt < 4; ++dt) oacc[qt][dt] = z4;
  }
  const short one_bf = (short)0x3F80;       // bf16 1.0
  const bf16x8 vones = {one_bf, one_bf, one_bf, one_bf,
                        one_bf, one_bf, one_bf, one_bf};

  const float C1 = 0.125f * 1.44269504089f;   // scale * log2(e)
  const float CL = 1.44269504089f;            // log2(e)
  const float CM = -12.0f * 1.44269504089f;   // offset * log2(e)

  const float* const bb =
      brow + (size_t)(q0 + w * 32 + quad * 4) * kL + 2 * col;

  for (int t = 0; t < 64; ++t) {
    const int buf = t & 1;
    const int k0 = t * 32;
    unsigned short* const Ks = KsBase + buf * 2304;
    unsigned short* const Vt = VtBase + buf * 2560;

    // prefetch next K/V tile into registers
    float4 pk0, pk1, pv0, pv1;
    const bool pf = (t < 63);
    if (pf) {
      const int kn = k0 + 32;
      pk0 = K4[(kn + keyA) * 16 + dcA];
      pk1 = K4[(kn + 16 + keyA) * 16 + dcA];
      pv0 = V4[(kn + 2 * jp) * 16 + dcv];
      pv1 = V4[(kn + 2 * jp + 1) * 16 + dcv];
    }

    // bias (float2, adjacent keys) + mask for this tile; issue early
    float2 bias2[2][4];
#pragma unroll
    for (int qt = 0; qt < 2; ++qt)
#pragma unroll
      for (int r = 0; r < 4; ++r)
        bias2[qt][r] = *(const float2*)(bb + (size_t)(qt * 16 + r) * kL + k0);
    const int2 mk = *(const int2*)&mrow[k0 + 2 * col];

    __syncthreads();                        // staging of tile t complete

    // ---- S = Q K^T (per wave: 32q x 32k; bk0=even keys, bk1=odd keys) ----
    f32x4 sacc[2][2];
#pragma unroll
    for (int qt = 0; qt < 2; ++qt) { sacc[qt][0] = z4; sacc[qt][1] = z4; }
#pragma unroll
    for (int kc = 0; kc < 2; ++kc) {
      const bf16x8 bk0 = *(const bf16x8*)&Ks[col * 72 + kc * 32 + quad * 8];
      const bf16x8 bk1 = *(const bf16x8*)&Ks[(16 + col) * 72 + kc * 32 + quad * 8];
#pragma unroll
      for (int qt = 0; qt < 2; ++qt) {
        sacc[qt][0] = __builtin_amdgcn_mfma_f32_16x16x32_bf16(
            qf[qt][kc], bk0, sacc[qt][0], 0, 0, 0);
        sacc[qt][1] = __builtin_amdgcn_mfma_f32_16x16x32_bf16(
            qf[qt][kc], bk1, sacc[qt][1], 0, 0, 0);
      }
    }

    // ---- softmax: p = exp2(fma(s,C1, fma(bias,CL,CM))), packed P write ----
#pragma unroll
    for (int qt = 0; qt < 2; ++qt)
#pragma unroll
      for (int r = 0; r < 4; ++r) {
        const float e0 = fmaf(sacc[qt][0][r], C1, fmaf(bias2[qt][r].x, CL, CM));
        const float e1 = fmaf(sacc[qt][1][r], C1, fmaf(bias2[qt][r].y, CL, CM));
        const float p0 = mk.x ? __builtin_amdgcn_exp2f(e0) : 0.0f;
        const float p1 = mk.y ? __builtin_amdgcn_exp2f(e1) : 0.0f;
        *(unsigned*)&Ps[(qt * 16 + quad * 4 + r) * 40 + 2 * col] =
            packbf2(p0, p1);
      }
    __threadfence_block();                  // order Ps writes before reads (same wave)

    // ---- O += P V ;  l += P . ones (on the MFMA pipe) ----
    bf16x8 ap[2];
#pragma unroll
    for (int qt = 0; qt < 2; ++qt)
      ap[qt] = *(const bf16x8*)&Ps[(qt * 16 + col) * 40 + quad * 8];
#pragma unroll
    for (int dt = 0; dt < 4; ++dt) {
      const bf16x8 bv = *(const bf16x8*)&Vt[(dt * 16 + col) * 40 + quad * 8];
#pragma unroll
      for (int qt = 0; qt < 2; ++qt)
        oacc[qt][dt] = __builtin_amdgcn_mfma_f32_16x16x32_bf16(
            ap[qt], bv, oacc[qt][dt], 0, 0, 0);
    }
#pragma unroll
    for (int qt = 0; qt < 2; ++qt)
      lacc[qt] = __builtin_amdgcn_mfma_f32_16x16x32_bf16(
          ap[qt], vones, lacc[qt], 0, 0, 0);

    // ---- write prefetched tile t+1 into the other buffer ----
    if (pf) {
      unsigned short* const Ksn = KsBase + (buf ^ 1) * 2304;
      unsigned short* const Vtn = VtBase + (buf ^ 1) * 2560;
      *(uint2*)&Ksn[rA * 72 + dcA * 4] =
          make_uint2(packbf2(pk0.x, pk0.y), packbf2(pk0.z, pk0.w));
      *(uint2*)&Ksn[(rA + 8) * 72 + dcA * 4] =
          make_uint2(packbf2(pk1.x, pk1.y), packbf2(pk1.z, pk1.w));
      *(unsigned*)&Vtn[(dcv * 4 + 0) * 40 + 2 * jp] = packbf2(pv0.x, pv1.x);
      *(unsigned*)&Vtn[(dcv * 4 + 1) * 40 + 2 * jp] = packbf2(pv0.y, pv1.y);
      *(unsigned*)&Vtn[(dcv * 4 + 2) * 40 + 2 * jp] = packbf2(pv0.z, pv1.z);
      *(unsigned*)&Vtn[(dcv * 4 + 3) * 40 + 2 * jp] = packbf2(pv0.w, pv1.w);
    }
  }

  // ---- epilogue: normalize (l from ones-MFMA, no reduction) and store ----
  float* const orow = outg + (bh * kL + q0) * kD;
#pragma unroll
  for (int qt = 0; qt < 2; ++qt)
#pragma unroll
    for (int r = 0; r < 4; ++r) {
      const float li = 1.0f / lacc[qt][r];
      float* op = orow + (size_t)(w * 32 + qt * 16 + quad * 4 + r) * kD + col;
#pragma unroll
      for (int dt = 0; dt < 4; ++dt)
        op[dt * 16] = oacc[qt][dt][r] * li;
    }
}

extern "C" void kernel_launch(void* const* d_in, const int* in_sizes, int n_in,
                              void* d_out, int out_size, void* d_ws, size_t ws_size,
                              hipStream_t stream) {
  const float* Q    = (const float*)d_in[0];
  const float* K    = (const float*)d_in[1];
  const float* V    = (const float*)d_in[2];
  const int*   mask = (const int*)d_in[3];
  const float* bias = (const float*)d_in[4];
  float* out = (float*)d_out;

  dim3 grid(kH, kL / 128, 4);   // (16, 16, 4) = 1024 blocks = 4/CU
  dim3 block(256);
  attn_fwd<<<grid, block, 0, stream>>>(Q, K, V, mask, bias, out);
}

// Round 5
// 327.636 us; speedup vs baseline: 1.1514x; 1.1514x over previous
//
#include <hip/hip_runtime.h>
#include <hip/hip_bf16.h>

// SelfAttention B=4 H=16 L=2048 D=64 fp32 in/out.
// Round 5: fix round-4's spill regression + LDS conflict + prefetch liveness.
//   - __launch_bounds__(256,2): round-4's (256,4) made the backend squeeze to
//     64 VGPRs and spill (WRITE_SIZE 33.5->64.5 MB). (256,2) gave 120 regs /
//     no spill in round 2; this config needs ~120 -> expect <=128, 4 blk/CU.
//   - Vt XOR swizzle: phys chunk = chunk ^ ((row>>2)&3); V staging write
//     conflicts 8-way -> 4-way. Reads apply the same swizzle.
//   - Prefetch loads issued after S-phase, stored at top of next iter:
//     register lifetime ~halved (store -> barrier -> read pipeline).
//   Everything else per round 4: QT=128 (32 q/wave), KT=32, even/odd key
//   permutation, packed P writes, exp2-fused softmax, ones-MFMA row sums.

constexpr int kH = 16;
constexpr int kL = 2048;
constexpr int kD = 64;

typedef __attribute__((ext_vector_type(8))) short bf16x8;
typedef __attribute__((ext_vector_type(4))) float f32x4;

__device__ __forceinline__ unsigned short f2bf(float f) {
  unsigned u = __float_as_uint(f);
  u += 0x7FFF + ((u >> 16) & 1);          // round-to-nearest-even
  return (unsigned short)(u >> 16);
}
__device__ __forceinline__ unsigned packbf2(float a, float b) {
  return (unsigned)f2bf(a) | ((unsigned)f2bf(b) << 16);
}

__global__ __launch_bounds__(256, 2)
void attn_fwd(const float* __restrict__ Qg, const float* __restrict__ Kg,
              const float* __restrict__ Vg, const int* __restrict__ maskg,
              const float* __restrict__ biasg, float* __restrict__ outg) {
  // LDS: Ks 2 bufs x 32 keys x 72 halves = 9216 B   [0, 9216)
  //      Vt 2 bufs x 64 d   x 40 halves = 10240 B   [9216, 19456)
  //      Ps 4 waves x 32 q  x 40 halves = 10240 B   [19456, 29696)
  // prologue aliases [0, 18432) as Qs 128 x 72 halves
  __shared__ __align__(16) char smem[29696];
  unsigned short* const KsBase = (unsigned short*)smem;
  unsigned short* const VtBase = (unsigned short*)(smem + 9216);
  unsigned short* const QsAll  = (unsigned short*)smem;

  const int tid  = threadIdx.x;
  const int lane = tid & 63;
  const int w    = tid >> 6;        // wave 0..3, owns q-rows w*32 .. w*32+31
  const int col  = lane & 15;
  const int quad = lane >> 4;
  const int h  = blockIdx.x;
  const int qb = blockIdx.y;
  const int b  = blockIdx.z;
  const int q0 = qb * 128;

  unsigned short* const Ps = (unsigned short*)(smem + 19456) + w * 1280;

  const size_t bh = (size_t)b * kH + h;
  const float4* const Q4 = (const float4*)(Qg + (bh * kL + q0) * kD);
  const float4* const K4 = (const float4*)(Kg + bh * kL * kD);
  const float4* const V4 = (const float4*)(Vg + bh * kL * kD);
  const float*  const brow = biasg + (size_t)b * kL * kL;
  const int*    const mrow = maskg + b * kL;

  // ---- prologue: Q fp32->bf16 into Qs (128 rows x 16 float4), load frags ----
#pragma unroll
  for (int i = 0; i < 8; ++i) {
    const int slot = tid + i * 256;
    const int row = slot >> 4, dc = slot & 15;
    const float4 v = Q4[slot];
    *(uint2*)&QsAll[row * 72 + dc * 4] =
        make_uint2(packbf2(v.x, v.y), packbf2(v.z, v.w));
  }
  __syncthreads();
  bf16x8 qf[2][2];
#pragma unroll
  for (int qt = 0; qt < 2; ++qt)
#pragma unroll
    for (int kc = 0; kc < 2; ++kc)
      qf[qt][kc] = *(const bf16x8*)
          &QsAll[(w * 32 + qt * 16 + col) * 72 + kc * 32 + quad * 8];
  __syncthreads();                          // Qs dead; smem now Ks/Vt/Ps

  // staging index split (coalesced 256B row reads)
  const int keyA = tid >> 4, dcA = tid & 15;   // K: global keys keyA, keyA+16
  // even/odd permuted Ks row: key j -> row (j&1)*16 + j/2  (keyA+16 -> rA+8)
  const int rA   = ((keyA & 1) << 4) + (keyA >> 1);
  const int jp   = tid >> 4, dcv = tid & 15;   // V: key pair (2jp, 2jp+1)
  // Vt swizzle: element V[key j][d] lives at row d, phys 8-half chunk
  //   (j>>3) ^ ((d>>2)&3), offset j&7. Staging: chunk = (jp>>2)^(dcv&3).
  const int vchunk = ((jp >> 2) ^ (dcv & 3)) << 3;
  const int voff   = (2 * jp) & 7;

  // ---- stage tile 0 into buf 0 ----
  {
    const float4 a  = K4[keyA * 16 + dcA];
    const float4 c  = K4[(16 + keyA) * 16 + dcA];
    const float4 v0 = V4[(2 * jp) * 16 + dcv];
    const float4 v1 = V4[(2 * jp + 1) * 16 + dcv];
    *(uint2*)&KsBase[rA * 72 + dcA * 4] =
        make_uint2(packbf2(a.x, a.y), packbf2(a.z, a.w));
    *(uint2*)&KsBase[(rA + 8) * 72 + dcA * 4] =
        make_uint2(packbf2(c.x, c.y), packbf2(c.z, c.w));
    *(unsigned*)&VtBase[(dcv * 4 + 0) * 40 + vchunk + voff] = packbf2(v0.x, v1.x);
    *(unsigned*)&VtBase[(dcv * 4 + 1) * 40 + vchunk + voff] = packbf2(v0.y, v1.y);
    *(unsigned*)&VtBase[(dcv * 4 + 2) * 40 + vchunk + voff] = packbf2(v0.z, v1.z);
    *(unsigned*)&VtBase[(dcv * 4 + 3) * 40 + vchunk + voff] = packbf2(v0.w, v1.w);
  }

  f32x4 oacc[2][4];                         // [qtile][dtile]
  f32x4 lacc[2];                            // row sums via ones-MFMA
  const f32x4 z4 = {0.f, 0.f, 0.f, 0.f};
#pragma unroll
  for (int qt = 0; qt < 2; ++qt) {
    lacc[qt] = z4;
#pragma unroll
    for (int dt = 0; dt < 4; ++dt) oacc[qt][dt] = z4;
  }
  const short one_bf = (short)0x3F80;       // bf16 1.0
  const bf16x8 vones = {one_bf, one_bf, one_bf, one_bf,
                        one_bf, one_bf, one_bf, one_bf};

  const float C1 = 0.125f * 1.44269504089f;   // scale * log2(e)
  const float CL = 1.44269504089f;            // log2(e)
  const float CM = -12.0f * 1.44269504089f;   // offset * log2(e)

  const float* const bb =
      brow + (size_t)(q0 + w * 32 + quad * 4) * kL + 2 * col;

  // prefetch registers: born after S-phase of t, die at top of t+1
  float4 pk0, pk1, pv0, pv1;

  for (int t = 0; t < 64; ++t) {
    const int buf = t & 1;
    const int k0 = t * 32;
    unsigned short* const Ks = KsBase + buf * 2304;
    unsigned short* const Vt = VtBase + buf * 2560;

    // ---- store tile t (prefetched during iter t-1) into its buffer ----
    // Safe: buf's previous contents (tile t-2) were read before barrier(t-1).
    if (t > 0) {
      *(uint2*)&Ks[rA * 72 + dcA * 4] =
          make_uint2(packbf2(pk0.x, pk0.y), packbf2(pk0.z, pk0.w));
      *(uint2*)&Ks[(rA + 8) * 72 + dcA * 4] =
          make_uint2(packbf2(pk1.x, pk1.y), packbf2(pk1.z, pk1.w));
      *(unsigned*)&Vt[(dcv * 4 + 0) * 40 + vchunk + voff] = packbf2(pv0.x, pv1.x);
      *(unsigned*)&Vt[(dcv * 4 + 1) * 40 + vchunk + voff] = packbf2(pv0.y, pv1.y);
      *(unsigned*)&Vt[(dcv * 4 + 2) * 40 + vchunk + voff] = packbf2(pv0.z, pv1.z);
      *(unsigned*)&Vt[(dcv * 4 + 3) * 40 + vchunk + voff] = packbf2(pv0.w, pv1.w);
    }

    // bias (float2, adjacent keys) + mask for this tile; issue before barrier
    float2 bias2[2][4];
#pragma unroll
    for (int qt = 0; qt < 2; ++qt)
#pragma unroll
      for (int r = 0; r < 4; ++r)
        bias2[qt][r] = *(const float2*)(bb + (size_t)(qt * 16 + r) * kL + k0);
    const int2 mk = *(const int2*)&mrow[k0 + 2 * col];

    __syncthreads();                        // tile t fully staged

    // ---- S = Q K^T (per wave: 32q x 32k; bk0=even keys, bk1=odd keys) ----
    f32x4 sacc[2][2];
#pragma unroll
    for (int qt = 0; qt < 2; ++qt) { sacc[qt][0] = z4; sacc[qt][1] = z4; }
#pragma unroll
    for (int kc = 0; kc < 2; ++kc) {
      const bf16x8 bk0 = *(const bf16x8*)&Ks[col * 72 + kc * 32 + quad * 8];
      const bf16x8 bk1 = *(const bf16x8*)&Ks[(16 + col) * 72 + kc * 32 + quad * 8];
#pragma unroll
      for (int qt = 0; qt < 2; ++qt) {
        sacc[qt][0] = __builtin_amdgcn_mfma_f32_16x16x32_bf16(
            qf[qt][kc], bk0, sacc[qt][0], 0, 0, 0);
        sacc[qt][1] = __builtin_amdgcn_mfma_f32_16x16x32_bf16(
            qf[qt][kc], bk1, sacc[qt][1], 0, 0, 0);
      }
    }

    // ---- issue prefetch loads for tile t+1 (consumed at top of t+1) ----
    if (t < 63) {
      const int kn = k0 + 32;
      pk0 = K4[(kn + keyA) * 16 + dcA];
      pk1 = K4[(kn + 16 + keyA) * 16 + dcA];
      pv0 = V4[(kn + 2 * jp) * 16 + dcv];
      pv1 = V4[(kn + 2 * jp + 1) * 16 + dcv];
    }

    // ---- softmax: p = exp2(fma(s,C1, fma(bias,CL,CM))), packed P write ----
#pragma unroll
    for (int qt = 0; qt < 2; ++qt)
#pragma unroll
      for (int r = 0; r < 4; ++r) {
        const float e0 = fmaf(sacc[qt][0][r], C1, fmaf(bias2[qt][r].x, CL, CM));
        const float e1 = fmaf(sacc[qt][1][r], C1, fmaf(bias2[qt][r].y, CL, CM));
        const float p0 = mk.x ? __builtin_amdgcn_exp2f(e0) : 0.0f;
        const float p1 = mk.y ? __builtin_amdgcn_exp2f(e1) : 0.0f;
        *(unsigned*)&Ps[(qt * 16 + quad * 4 + r) * 40 + 2 * col] =
            packbf2(p0, p1);
      }
    __threadfence_block();                  // order Ps writes before reads

    // ---- O += P V ;  l += P . ones (on the MFMA pipe) ----
    bf16x8 ap[2];
#pragma unroll
    for (int qt = 0; qt < 2; ++qt)
      ap[qt] = *(const bf16x8*)&Ps[(qt * 16 + col) * 40 + quad * 8];
#pragma unroll
    for (int dt = 0; dt < 4; ++dt) {
      // Vt read with swizzle: row R = dt*16+col, phys chunk = quad^(col>>2)
      const bf16x8 bv = *(const bf16x8*)
          &Vt[(dt * 16 + col) * 40 + ((quad ^ (col >> 2)) << 3)];
#pragma unroll
      for (int qt = 0; qt < 2; ++qt)
        oacc[qt][dt] = __builtin_amdgcn_mfma_f32_16x16x32_bf16(
            ap[qt], bv, oacc[qt][dt], 0, 0, 0);
    }
#pragma unroll
    for (int qt = 0; qt < 2; ++qt)
      lacc[qt] = __builtin_amdgcn_mfma_f32_16x16x32_bf16(
          ap[qt], vones, lacc[qt], 0, 0, 0);
  }

  // ---- epilogue: normalize (l from ones-MFMA, no reduction) and store ----
  float* const orow = outg + (bh * kL + q0) * kD;
#pragma unroll
  for (int qt = 0; qt < 2; ++qt)
#pragma unroll
    for (int r = 0; r < 4; ++r) {
      const float li = 1.0f / lacc[qt][r];
      float* op = orow + (size_t)(w * 32 + qt * 16 + quad * 4 + r) * kD + col;
#pragma unroll
      for (int dt = 0; dt < 4; ++dt)
        op[dt * 16] = oacc[qt][dt][r] * li;
    }
}

extern "C" void kernel_launch(void* const* d_in, const int* in_sizes, int n_in,
                              void* d_out, int out_size, void* d_ws, size_t ws_size,
                              hipStream_t stream) {
  const float* Q    = (const float*)d_in[0];
  const float* K    = (const float*)d_in[1];
  const float* V    = (const float*)d_in[2];
  const int*   mask = (const int*)d_in[3];
  const float* bias = (const float*)d_in[4];
  float* out = (float*)d_out;

  dim3 grid(kH, kL / 128, 4);   // (16, 16, 4) = 1024 blocks
  dim3 block(256);
  attn_fwd<<<grid, block, 0, stream>>>(Q, K, V, mask, bias, out);
}